// Round 8
// baseline (523.667 us; speedup 1.0000x reference)
//
#include <hip/hip_runtime.h>
#include <hip/hip_bf16.h>
#include <math.h>

#define H 1024
#define N1 2048
#define BATCH 8
#define SEQ 4096
#define M_TOT (BATCH*SEQ)
#define EPS 1e-5f
#define MIX 0.1f

typedef __attribute__((ext_vector_type(8))) short bf16x8;
typedef __attribute__((ext_vector_type(4))) float f32x4;
typedef unsigned int uint_t;

static __device__ __forceinline__ float bf2f(unsigned short u) {
    return __uint_as_float(((unsigned)u) << 16);
}
static __device__ __forceinline__ unsigned short f2bf(float x) {
    __hip_bfloat16 h = __float2bfloat16(x);
    return *reinterpret_cast<unsigned short*>(&h);
}
static __device__ __forceinline__ void gload16(const void* g, void* l) {
    __builtin_amdgcn_global_load_lds(
        (const __attribute__((address_space(1))) unsigned int*)g,
        (__attribute__((address_space(3))) unsigned int*)l,
        16, 0, 0);
}
static __device__ __forceinline__ int perm2h(int c)  { return ((c & 1023) << 1) | (c >> 10); }

// ---------- f32 -> bf16 bulk convert ----------
__global__ __launch_bounds__(256) void cvt_f32_bf16(
    const float* __restrict__ in, unsigned short* __restrict__ out, size_t n)
{
    size_t i = ((size_t)blockIdx.x * 256 + threadIdx.x) * 8;
    if (i >= n) return;
    float4 a = *(const float4*)(in + i);
    float4 b = *(const float4*)(in + i + 4);
    union { unsigned short u[8]; uint4 v; } p;
    p.u[0] = f2bf(a.x); p.u[1] = f2bf(a.y); p.u[2] = f2bf(a.z); p.u[3] = f2bf(a.w);
    p.u[4] = f2bf(b.x); p.u[5] = f2bf(b.y); p.u[6] = f2bf(b.z); p.u[7] = f2bf(b.w);
    *(uint4*)(out + i) = p.v;
}

// ---------- WtT: out[perm2h(c)][r] = Wt[r][c] ----------
__global__ __launch_bounds__(256) void transpose_wt(
    const float* __restrict__ in, unsigned short* __restrict__ out)
{
    __shared__ float tile[64][65];
    const int c0 = blockIdx.x * 64, r0 = blockIdx.y * 64;
    const int tc = threadIdx.x & 63, tr4 = (threadIdx.x >> 6) * 16;
    #pragma unroll
    for (int rr = 0; rr < 16; ++rr)
        tile[tr4 + rr][tc] = in[(size_t)(r0 + tr4 + rr) * N1 + c0 + tc];
    __syncthreads();
    #pragma unroll
    for (int rr = 0; rr < 16; ++rr)
        out[(size_t)perm2h(c0 + tr4 + rr) * H + r0 + tc] = f2bf(tile[tc][tr4 + rr]);
}

// ---------- WfT: out[n][k] = Wf[invperm(k)][n] ----------
__global__ __launch_bounds__(256) void transpose_wf(
    const float* __restrict__ in, unsigned short* __restrict__ out)
{
    __shared__ float tile[64][65];
    const int n0 = blockIdx.x * 64, k0 = blockIdx.y * 64;
    const int tc = threadIdx.x & 63, tr4 = (threadIdx.x >> 6) * 16;
    #pragma unroll
    for (int rr = 0; rr < 16; ++rr) {
        const int k = k0 + tr4 + rr;
        tile[tr4 + rr][tc] = in[(size_t)((k >> 1) | ((k & 1) << 10)) * H + n0 + tc];
    }
    __syncthreads();
    #pragma unroll
    for (int rr = 0; rr < 16; ++rr)
        out[(size_t)(n0 + tr4 + rr) * N1 + k0 + tc] = f2bf(tile[tc][tr4 + rr]);
}

// ================= 256x256 8-phase MFMA GEMM, BK=64, counted lgkm =================
// MODE 0: gemm1 (bf16 out + fused stats). MODE 1: gemm2 (f32 out).
// MODE 2: ablation — full skeleton, MFMA replaced by keepalives (rule #17).
#define VM4 asm volatile("s_waitcnt vmcnt(4)" ::: "memory")
#define VM0 asm volatile("s_waitcnt vmcnt(0)" ::: "memory")
#define LGKMN(N) do { asm volatile("s_waitcnt lgkmcnt(" #N ")" ::: "memory"); \
                      __builtin_amdgcn_sched_barrier(0); } while (0)

#define STG(X, BB, HH, CC, TT) \
    gload16(X##g + (size_t)((HH)*128 + (CC)*64) * KDIM + (TT)*64, \
            &X##s[BB][(HH)*8192 + (CC)*4096 + t*8])
#define STAGE_HT(X, BB, HH, TT) do { STG(X, BB, HH, 0, TT); STG(X, BB, HH, 1, TT); } while(0)

#define LDA(BB, MF, KS) (*(const bf16x8*)&As[BB][(wr*128 + (MF)*16 + fr)*64 + ((((KS)*4 + lg) ^ rsw))*8])
#define LDB(BB, NF, KS) (*(const bf16x8*)&Bs[BB][(wc*64  + (NF)*16 + fr)*64 + ((((KS)*4 + lg) ^ rsw))*8])

// Phase: {ks0 reads | ks1 reads | stage} barrier; lgkm(LGN) -> 8 MFMA(ks0);
// lgkm(0) -> 8 MFMA(ks1); counted vm; barrier.  LGN = ks1-group size (6 at Q0, 2 else).
#define PHASE(BB, Q, LGN, STAGE_STMT, VM_STMT) do {                             \
    if ((Q) == 0) {                                                             \
        _Pragma("unroll")                                                       \
        for (int nf = 0; nf < 4; ++nf) bfr[nf][0] = LDB(BB, nf, 0);             \
    }                                                                           \
    afr[0][0] = LDA(BB, 2*(Q), 0); afr[1][0] = LDA(BB, 2*(Q)+1, 0);             \
    __builtin_amdgcn_sched_barrier(0);  /* pin ks0|ks1 group boundary */        \
    if ((Q) == 0) {                                                             \
        _Pragma("unroll")                                                       \
        for (int nf = 0; nf < 4; ++nf) bfr[nf][1] = LDB(BB, nf, 1);             \
    }                                                                           \
    afr[0][1] = LDA(BB, 2*(Q), 1); afr[1][1] = LDA(BB, 2*(Q)+1, 1);             \
    STAGE_STMT;                                                                 \
    __builtin_amdgcn_sched_barrier(0);  /* pin reads above barrier */           \
    __builtin_amdgcn_s_barrier();                                               \
    LGKMN(LGN);                                                                 \
    __builtin_amdgcn_s_setprio(1);                                              \
    if constexpr (MODE != 2) {                                                  \
        _Pragma("unroll")                                                       \
        for (int mf = 0; mf < 2; ++mf)                                          \
            _Pragma("unroll")                                                   \
            for (int nf = 0; nf < 4; ++nf)                                      \
                acc[2*(Q)+mf][nf] = __builtin_amdgcn_mfma_f32_16x16x32_bf16(    \
                    afr[mf][0], bfr[nf][0], acc[2*(Q)+mf][nf], 0, 0, 0);        \
        LGKMN(0);                                                               \
        _Pragma("unroll")                                                       \
        for (int mf = 0; mf < 2; ++mf)                                          \
            _Pragma("unroll")                                                   \
            for (int nf = 0; nf < 4; ++nf)                                      \
                acc[2*(Q)+mf][nf] = __builtin_amdgcn_mfma_f32_16x16x32_bf16(    \
                    afr[mf][1], bfr[nf][1], acc[2*(Q)+mf][nf], 0, 0, 0);        \
    } else {                                                                    \
        LGKMN(0);                                                               \
        asm volatile("" :: "v"(afr[0][0]), "v"(afr[0][1]),                      \
                           "v"(afr[1][0]), "v"(afr[1][1]));                     \
        if ((Q) == 0)                                                           \
            asm volatile("" :: "v"(bfr[0][0]), "v"(bfr[0][1]), "v"(bfr[1][0]),  \
                               "v"(bfr[1][1]), "v"(bfr[2][0]), "v"(bfr[2][1]),  \
                               "v"(bfr[3][0]), "v"(bfr[3][1]));                 \
        _Pragma("unroll")                                                       \
        for (int nf = 0; nf < 4; ++nf) {                                        \
            asm volatile("" : "+v"(acc[2*(Q)][nf]));                            \
            asm volatile("" : "+v"(acc[2*(Q)+1][nf]));                          \
        }                                                                       \
    }                                                                           \
    __builtin_amdgcn_s_setprio(0);                                              \
    VM_STMT;                                                                    \
    __builtin_amdgcn_s_barrier();                                               \
} while (0)

template<int KDIM, int MODE>
__global__ __launch_bounds__(512, 2) void gemm8(
    const unsigned short* __restrict__ A,
    const unsigned short* __restrict__ Bt,
    const float* __restrict__ bias,
    void* __restrict__ Cout,
    float* __restrict__ sums)
{
    __shared__ __align__(16) unsigned short As[2][16384];
    __shared__ __align__(16) unsigned short Bs[2][16384];

    const int t    = threadIdx.x;
    const int lane = t & 63;
    const int wid  = t >> 6;
    const int wr   = wid >> 2;   // 0..1
    const int wc   = wid & 3;    // 0..3

    int m0, n0;
    if constexpr (MODE == 0) {        // 1024 blocks: 128/XCD
        const unsigned wg = ((blockIdx.x & 7) << 7) | (blockIdx.x >> 3);
        n0 = (wg & 7) * 256;
        m0 = (wg >> 3) * 256;
    } else if constexpr (MODE == 1) { // 512 blocks: 64/XCD
        const unsigned wg = ((blockIdx.x & 7) << 6) | (blockIdx.x >> 3);
        n0 = (wg & 3) * 256;
        m0 = (wg >> 2) * 256;
    } else {                          // ablation, 2048 blocks: wrap m
        n0 = (blockIdx.x & 7) * 256;
        m0 = ((blockIdx.x >> 3) & 127) * 256;
    }

    const int srow = t >> 3;
    const int ssw  = srow & 7;
    const int gk   = ((t & 7) ^ ssw) * 8;
    const unsigned short* Ag = A  + (size_t)(m0 + srow) * KDIM + gk;
    const unsigned short* Bg = Bt + (size_t)(n0 + srow) * KDIM + gk;

    const int fr  = lane & 15;
    const int lg  = lane >> 4;
    const int rsw = fr & 7;

    f32x4 acc[8][4] = {};
    bf16x8 bfr[4][2];
    bf16x8 afr[2][2];

    constexpr int NITER = KDIM / 128;

    STAGE_HT(A, 0, 0, 0); STAGE_HT(A, 0, 1, 0);
    STAGE_HT(B, 0, 0, 0); STAGE_HT(B, 0, 1, 0);
    STAGE_HT(B, 1, 0, 1); STAGE_HT(B, 1, 1, 1);
    VM4;
    __builtin_amdgcn_s_barrier();

    for (int it = 0; it < NITER; ++it) {
        const int  T1   = 2 * it + 1;
        const int  T2   = 2 * it + 2;
        const int  T3   = 2 * it + 3;
        const bool more = (it + 1 < NITER);
        PHASE(0, 0, 6, STAGE_HT(A, 1, 0, T1), );                                  // ph1
        PHASE(0, 1, 2, STAGE_HT(A, 1, 1, T1), );                                  // ph2
        PHASE(0, 2, 2, if (more) STAGE_HT(B, 0, 0, T2), );                        // ph3
        PHASE(0, 3, 2, if (more) STAGE_HT(B, 0, 1, T2), if (more) { VM4; } else { VM0; }); // ph4
        PHASE(1, 0, 6, if (more) STAGE_HT(A, 0, 0, T2), );                        // ph5
        PHASE(1, 1, 2, if (more) STAGE_HT(A, 0, 1, T2), );                        // ph6
        PHASE(1, 2, 2, if (more) STAGE_HT(B, 1, 0, T3), );                        // ph7
        PHASE(1, 3, 2, if (more) STAGE_HT(B, 1, 1, T3), if (more) { VM4; });      // ph8
    }

    // ---------------- epilogue ----------------
    const int colbase = n0 + wc * 64;
    if constexpr (MODE == 0) {
        unsigned short* c1 = (unsigned short*)Cout;
        #pragma unroll
        for (int nf = 0; nf < 4; ++nf) {
            const int col = colbase + nf * 16 + fr;
            const float bb = bias[(col >> 1) | ((col & 1) << 10)];  // invperm
            #pragma unroll
            for (int mf = 0; mf < 8; ++mf)
                #pragma unroll
                for (int r = 0; r < 4; ++r)
                    acc[mf][nf][r] += bb;
        }
        float lc[4] = {0, 0, 0, 0}, ls[4] = {0, 0, 0, 0};
        #pragma unroll
        for (int nf = 0; nf < 4; ++nf)
            #pragma unroll
            for (int mf = 0; mf < 8; ++mf)
                #pragma unroll
                for (int r = 0; r < 4; ++r) {
                    const float v = acc[mf][nf][r];
                    const float oth = __shfl_xor(v, 1);
                    const float re = (fr & 1) ? oth : v;
                    const float im = (fr & 1) ? v : oth;
                    const float rq = rsqrtf(fmaxf(re * re + im * im, 1e-30f));
                    lc[nf] += re * rq;
                    ls[nf] += im * rq;
                }
        #pragma unroll
        for (int nf = 0; nf < 4; ++nf) {
            lc[nf] += __shfl_xor(lc[nf], 16); lc[nf] += __shfl_xor(lc[nf], 32);
            ls[nf] += __shfl_xor(ls[nf], 16); ls[nf] += __shfl_xor(ls[nf], 32);
        }
        if (lane < 16 && !(lane & 1)) {
            const int b = m0 >> 12;
            #pragma unroll
            for (int nf = 0; nf < 4; ++nf) {
                const int hh = (colbase + nf * 16 + fr) >> 1;
                atomicAdd(&sums[(b * 2 + 0) * H + hh], lc[nf]);
                atomicAdd(&sums[(b * 2 + 1) * H + hh], ls[nf]);
            }
        }
        unsigned short* cst = &As[0][0] + wid * 2048;
        const int row16 = lane >> 2;
        #pragma unroll
        for (int mf = 0; mf < 8; ++mf) {
            #pragma unroll
            for (int nf = 0; nf < 4; ++nf)
                #pragma unroll
                for (int r = 0; r < 4; ++r)
                    cst[(lg * 4 + r) * 68 + nf * 16 + fr] = f2bf(acc[mf][nf][r]);
            const size_t grow = (size_t)(m0 + wr * 128 + mf * 16 + row16);
            #pragma unroll
            for (int c = 0; c < 2; ++c) {
                const int chunk = (lane & 3) + c * 4;
                uint4 v = *(const uint4*)&cst[row16 * 68 + chunk * 8];
                *(uint4*)&c1[grow * N1 + colbase + chunk * 8] = v;
            }
        }
    } else if constexpr (MODE == 1) {
        float* o = (float*)Cout;
        #pragma unroll
        for (int nf = 0; nf < 4; ++nf) {
            const int col = colbase + nf * 16 + fr;
            const float bb = bias[col];
            #pragma unroll
            for (int mf = 0; mf < 8; ++mf) {
                #pragma unroll
                for (int r = 0; r < 4; ++r) {
                    const size_t row = (size_t)(m0 + wr * 128 + mf * 16 + lg * 4 + r);
                    o[row * H + col] = acc[mf][nf][r] + bb;
                }
            }
        }
    } else {
        // minimal epilogue: fold acc, tiny store (overwritten by real gemm1 later)
        float s = 0.f;
        #pragma unroll
        for (int mf = 0; mf < 8; ++mf)
            #pragma unroll
            for (int nf = 0; nf < 4; ++nf)
                s += acc[mf][nf][0] + acc[mf][nf][1] + acc[mf][nf][2] + acc[mf][nf][3];
        ((unsigned short*)Cout)[(size_t)blockIdx.x * 512 + t] = f2bf(s);
    }
}

// ---------- fold phase_shifts + means into P,Q per (b,h) ----------
__global__ void finalize_pq(const float* __restrict__ sums, const float* __restrict__ ps,
                            float* __restrict__ P, float* __restrict__ Q)
{
    int i = blockIdx.x * 256 + threadIdx.x;   // 8192
    int b = i >> 10, h = i & (H - 1);
    float mc = sums[(b * 2 + 0) * H + h] * (1.0f / SEQ);
    float ms = sums[(b * 2 + 1) * H + h] * (1.0f / SEQ);
    float cp = cosf(ps[h]), sp = sinf(ps[h]);
    P[i] = mc * cp + ms * sp;
    Q[i] = ms * cp - mc * sp;
}

// ---------- phase mix, in place, interleaved pairs ----------
__global__ __launch_bounds__(256) void phase_mix(
    unsigned short* __restrict__ c1, const float* __restrict__ P,
    const float* __restrict__ Q)
{
    const size_t total = (size_t)M_TOT * N1 / 8;
    for (size_t q = (size_t)blockIdx.x * 256 + threadIdx.x; q < total;
         q += (size_t)gridDim.x * 256) {
        const size_t m = q >> 8;
        const int off = ((int)q & 255) * 8;
        const int b = (int)(m >> 12);
        const int h0 = off >> 1;
        uint4* cu = (uint4*)c1;
        const size_t idx = ((size_t)m * N1 + off) >> 3;
        uint4 v = cu[idx];
        float4 Pv = *(const float4*)&P[b * H + h0];
        float4 Qv = *(const float4*)&Q[b * H + h0];
        const uint_t w[4] = { v.x, v.y, v.z, v.w };
        const float Pk[4] = { Pv.x, Pv.y, Pv.z, Pv.w };
        const float Qk[4] = { Qv.x, Qv.y, Qv.z, Qv.w };
        uint_t o[4];
        #pragma unroll
        for (int e = 0; e < 4; ++e) {
            float r  = bf2f(w[e] & 0xffff);
            float im = bf2f(w[e] >> 16);
            float tt = r * r + im * im;
            float minv = rsqrtf(fmaxf(tt, 1e-30f));
            float d = MIX * (r * Pk[e] + im * Qk[e]) * minv;
            float d2 = d * d;
            float cd = 1.0f - d2 * (0.5f - d2 * (1.0f / 24.0f));
            float sd = d * (1.0f - d2 * ((1.0f / 6.0f) - d2 * (1.0f / 120.0f)));
            float sc = sqrtf(tt + EPS) * minv;
            o[e] = (uint_t)f2bf(sc * (r * cd - im * sd))
                 | ((uint_t)f2bf(sc * (im * cd + r * sd)) << 16);
        }
        v.x = o[0]; v.y = o[1]; v.z = o[2]; v.w = o[3];
        cu[idx] = v;
    }
}

extern "C" void kernel_launch(void* const* d_in, const int* in_sizes, int n_in,
                              void* d_out, int out_size, void* d_ws, size_t ws_size,
                              hipStream_t stream) {
    const float* x  = (const float*)d_in[0];
    const float* Wt = (const float*)d_in[1];
    const float* bt = (const float*)d_in[2];
    const float* Wf = (const float*)d_in[3];
    const float* bf = (const float*)d_in[4];
    const float* ps = (const float*)d_in[5];
    float* out = (float*)d_out;

    const size_t c1_bytes   = (size_t)M_TOT * N1 * 2;
    const size_t wft_bytes  = (size_t)H * N1 * 2;
    const size_t sums_bytes = (size_t)BATCH * 2 * H * 4;
    const size_t pq_bytes   = (size_t)BATCH * H * 4;
    if (ws_size < c1_bytes + wft_bytes + sums_bytes + 2 * pq_bytes) return;

    unsigned short* c1  = (unsigned short*)d_ws;
    unsigned short* WfT = (unsigned short*)((char*)d_ws + c1_bytes);
    float* sums = (float*)((char*)d_ws + c1_bytes + wft_bytes);
    float* Pb   = (float*)((char*)d_ws + c1_bytes + wft_bytes + sums_bytes);
    float* Qb   = (float*)((char*)d_ws + c1_bytes + wft_bytes + sums_bytes + pq_bytes);

    unsigned short* xb  = (unsigned short*)d_out;                      // 64 Mi
    unsigned short* WtT = (unsigned short*)d_out + (size_t)M_TOT * H;  // 4 Mi

    hipMemsetAsync(sums, 0, sums_bytes, stream);

    cvt_f32_bf16<<<dim3((unsigned)(((size_t)M_TOT * H / 8 + 255) / 256)), 256, 0, stream>>>(
        x, xb, (size_t)M_TOT * H);
    transpose_wt<<<dim3(N1 / 64, H / 64), 256, 0, stream>>>(Wt, WtT);
    transpose_wf<<<dim3(H / 64, N1 / 64), 256, 0, stream>>>(Wf, WfT);

    // ABLATION probe: skeleton-only (no MFMA), 2048 blocks; c1 garbage is
    // fully overwritten by the real gemm1 below.
    gemm8<H, 2><<<dim3(2048), 512, 0, stream>>>(xb, WtT, bt, (void*)c1, nullptr);

    gemm8<H, 0><<<dim3(1024), 512, 0, stream>>>(xb, WtT, bt, (void*)c1, sums);

    finalize_pq<<<dim3(BATCH * H / 256), 256, 0, stream>>>(sums, ps, Pb, Qb);
    phase_mix<<<dim3(4096), 256, 0, stream>>>(c1, Pb, Qb);

    gemm8<N1, 1><<<dim3(512), 512, 0, stream>>>(c1, WfT, bf, (void*)out, nullptr);
}

// Round 9
// 361.341 us; speedup vs baseline: 1.4492x; 1.4492x over previous
//
#include <hip/hip_runtime.h>
#include <hip/hip_bf16.h>
#include <math.h>

#define H 1024
#define N1 2048
#define BATCH 8
#define SEQ 4096
#define M_TOT (BATCH*SEQ)
#define EPS 1e-5f
#define MIX 0.1f

typedef __attribute__((ext_vector_type(8))) short bf16x8;
typedef __attribute__((ext_vector_type(4))) float f32x4;
typedef unsigned int uint_t;

static __device__ __forceinline__ float bf2f(unsigned short u) {
    return __uint_as_float(((unsigned)u) << 16);
}
static __device__ __forceinline__ unsigned short f2bf(float x) {
    __hip_bfloat16 h = __float2bfloat16(x);
    return *reinterpret_cast<unsigned short*>(&h);
}
static __device__ __forceinline__ void gload16(const void* g, void* l) {
    __builtin_amdgcn_global_load_lds(
        (const __attribute__((address_space(1))) unsigned int*)g,
        (__attribute__((address_space(3))) unsigned int*)l,
        16, 0, 0);
}
static __device__ __forceinline__ int perm2h(int c)  { return ((c & 1023) << 1) | (c >> 10); }

// ---------- f32 -> bf16 bulk convert ----------
__global__ __launch_bounds__(256) void cvt_f32_bf16(
    const float* __restrict__ in, unsigned short* __restrict__ out, size_t n)
{
    size_t i = ((size_t)blockIdx.x * 256 + threadIdx.x) * 8;
    if (i >= n) return;
    float4 a = *(const float4*)(in + i);
    float4 b = *(const float4*)(in + i + 4);
    union { unsigned short u[8]; uint4 v; } p;
    p.u[0] = f2bf(a.x); p.u[1] = f2bf(a.y); p.u[2] = f2bf(a.z); p.u[3] = f2bf(a.w);
    p.u[4] = f2bf(b.x); p.u[5] = f2bf(b.y); p.u[6] = f2bf(b.z); p.u[7] = f2bf(b.w);
    *(uint4*)(out + i) = p.v;
}

// ---------- WtT: out[perm2h(c)][r] = Wt[r][c] ----------
__global__ __launch_bounds__(256) void transpose_wt(
    const float* __restrict__ in, unsigned short* __restrict__ out)
{
    __shared__ float tile[64][65];
    const int c0 = blockIdx.x * 64, r0 = blockIdx.y * 64;
    const int tc = threadIdx.x & 63, tr4 = (threadIdx.x >> 6) * 16;
    #pragma unroll
    for (int rr = 0; rr < 16; ++rr)
        tile[tr4 + rr][tc] = in[(size_t)(r0 + tr4 + rr) * N1 + c0 + tc];
    __syncthreads();
    #pragma unroll
    for (int rr = 0; rr < 16; ++rr)
        out[(size_t)perm2h(c0 + tr4 + rr) * H + r0 + tc] = f2bf(tile[tc][tr4 + rr]);
}

// ---------- WfT: out[n][k] = Wf[invperm(k)][n] ----------
__global__ __launch_bounds__(256) void transpose_wf(
    const float* __restrict__ in, unsigned short* __restrict__ out)
{
    __shared__ float tile[64][65];
    const int n0 = blockIdx.x * 64, k0 = blockIdx.y * 64;
    const int tc = threadIdx.x & 63, tr4 = (threadIdx.x >> 6) * 16;
    #pragma unroll
    for (int rr = 0; rr < 16; ++rr) {
        const int k = k0 + tr4 + rr;
        tile[tr4 + rr][tc] = in[(size_t)((k >> 1) | ((k & 1) << 10)) * H + n0 + tc];
    }
    __syncthreads();
    #pragma unroll
    for (int rr = 0; rr < 16; ++rr)
        out[(size_t)(n0 + tr4 + rr) * N1 + k0 + tc] = f2bf(tile[tc][tr4 + rr]);
}

// ================= 256x256 8-phase MFMA GEMM, BK=64, cross-phase pipelined =========
// Each phase: reads NEXT phase's A-frags, leaves them in flight (lgkmcnt(4), never 0)
// -> LDS service overlaps the MFMA cluster. Single-ks MFMA groups (4mf x 4nf).
// vmcnt gates moved BEFORE the cross-buffer A-prefetch at ph4/ph8.
#define VMW(N) asm volatile("s_waitcnt vmcnt(" #N ")" ::: "memory")
#define SB __builtin_amdgcn_sched_barrier(0)

#define STG(X, BB, HH, CC, TT) \
    gload16(X##g + (size_t)((HH)*128 + (CC)*64) * KDIM + (TT)*64, \
            &X##s[BB][(HH)*8192 + (CC)*4096 + t*8])
#define STAGE_HT(X, BB, HH, TT) do { STG(X, BB, HH, 0, TT); STG(X, BB, HH, 1, TT); } while(0)

#define LDA(BB, MF, KS) (*(const bf16x8*)&As[BB][(wr*128 + (MF)*16 + fr)*64 + ((((KS)*4 + lg) ^ rsw))*8])
#define LDB(BB, NF, KS) (*(const bf16x8*)&Bs[BB][(wc*64  + (NF)*16 + fr)*64 + ((((KS)*4 + lg) ^ rsw))*8])

#define LOADB(BB, KS) do {                                                      \
    _Pragma("unroll")                                                           \
    for (int nf = 0; nf < 4; ++nf) bfr[nf] = LDB(BB, nf, KS); } while (0)
#define LOADA(AN, BB, MFQ, KS) do {                                             \
    _Pragma("unroll")                                                           \
    for (int i = 0; i < 4; ++i) AN[i] = LDA(BB, (MFQ)*4 + i, KS); } while (0)
#define MFMAS(AC, MFQ) do {                                                     \
    _Pragma("unroll")                                                           \
    for (int i = 0; i < 4; ++i)                                                 \
        _Pragma("unroll")                                                       \
        for (int nf = 0; nf < 4; ++nf)                                          \
            acc[(MFQ)*4 + i][nf] = __builtin_amdgcn_mfma_f32_16x16x32_bf16(     \
                AC[i], bfr[nf], acc[(MFQ)*4 + i][nf], 0, 0, 0); } while (0)

// Phase: [vm-gate][B-reads][A-prefetch (next phase)][stage] bar; lgkm(4); MFMA; bar.
#define PH(VMPRE, BLOAD, ALOAD, STAGE_STMT, MFMA_STMT) do {                     \
    VMPRE; SB;                                                                  \
    BLOAD; SB;                                                                  \
    ALOAD; SB;                                                                  \
    STAGE_STMT; SB;                                                             \
    __builtin_amdgcn_s_barrier();                                               \
    asm volatile("s_waitcnt lgkmcnt(4)" ::: "memory");                          \
    SB;                                                                         \
    __builtin_amdgcn_s_setprio(1);                                              \
    MFMA_STMT;                                                                  \
    __builtin_amdgcn_s_setprio(0);                                              \
    __builtin_amdgcn_s_barrier();                                               \
} while (0)

#define NOP ((void)0)

template<int KDIM, bool G1>
__global__ __launch_bounds__(512, 2) void gemm8(
    const unsigned short* __restrict__ A,
    const unsigned short* __restrict__ Bt,
    const float* __restrict__ bias,
    void* __restrict__ Cout,
    float* __restrict__ sums)
{
    __shared__ __align__(16) unsigned short As[2][16384];
    __shared__ __align__(16) unsigned short Bs[2][16384];

    const int t    = threadIdx.x;
    const int lane = t & 63;
    const int wid  = t >> 6;
    const int wr   = wid >> 2;   // 0..1
    const int wc   = wid & 3;    // 0..3

    int m0, n0;
    if (G1) {   // 1024 blocks: 128/XCD, n-fastest within XCD
        const unsigned wg = ((blockIdx.x & 7) << 7) | (blockIdx.x >> 3);
        n0 = (wg & 7) * 256;
        m0 = (wg >> 3) * 256;
    } else {    // 512 blocks: 64/XCD
        const unsigned wg = ((blockIdx.x & 7) << 6) | (blockIdx.x >> 3);
        n0 = (wg & 3) * 256;
        m0 = (wg >> 2) * 256;
    }

    // staging: thread t -> rows {h*128 + c*64 + (t>>3)}, k-slot (t&7), 3-bit pre-swizzled src
    const int srow = t >> 3;
    const int ssw  = srow & 7;
    const int gk   = ((t & 7) ^ ssw) * 8;
    const unsigned short* Ag = A  + (size_t)(m0 + srow) * KDIM + gk;
    const unsigned short* Bg = Bt + (size_t)(n0 + srow) * KDIM + gk;

    // reader: row bits 0-2 = fr bits 0-2 -> same involution (0 conflicts, verified r5)
    const int fr  = lane & 15;
    const int lg  = lane >> 4;
    const int rsw = fr & 7;

    f32x4 acc[8][4] = {};
    bf16x8 bfr[4];     // current B quadrant, single ks
    bf16x8 aX[4];      // A ping
    bf16x8 aY[4];      // A pong

    constexpr int NITER = KDIM / 128;   // 2 K-tiles (E=buf0, O=buf1) per iteration

    // prologue: E0.A, E0.B, O0.B staged; wait E0 landed (O0.B stays in flight)
    STAGE_HT(A, 0, 0, 0); STAGE_HT(A, 0, 1, 0);
    STAGE_HT(B, 0, 0, 0); STAGE_HT(B, 0, 1, 0);
    STAGE_HT(B, 1, 0, 1); STAGE_HT(B, 1, 1, 1);
    VMW(4);
    SB;
    __builtin_amdgcn_s_barrier();
    SB;
    LOADA(aX, 0, 0, 0);   // preload E0.A mf0-3 ks0 (drained by ph1's lgkm)
    SB;

    for (int it = 0; it < NITER; ++it) {
        const int  T1   = 2 * it + 1;
        const int  T2   = 2 * it + 2;
        const int  T3   = 2 * it + 3;
        const bool more = (it + 1 < NITER);
        // ph1: MFMA E/ks0/mf0-3 (aX); prefetch aY<-E.A mf4-7 ks0; stage O.A h0
        PH(NOP, LOADB(0,0), LOADA(aY,0,1,0), STAGE_HT(A,1,0,T1), MFMAS(aX,0));
        // ph2: MFMA E/ks0/mf4-7 (aY); prefetch aX<-E.A mf0-3 ks1; stage O.A h1
        PH(NOP, NOP, LOADA(aX,0,0,1), STAGE_HT(A,1,1,T1), MFMAS(aY,1));
        // ph3: MFMA E/ks1/mf0-3 (aX); B<-E.B ks1; prefetch aY<-E.A mf4-7 ks1
        PH(NOP, LOADB(0,1), LOADA(aY,0,1,1), if (more) STAGE_HT(B,0,0,T2), MFMAS(aX,0));
        // ph4: vm-gate O-tile; MFMA E/ks1/mf4-7 (aY); prefetch aX<-O.A mf0-3 ks0 (buf1)
        PH(if (more) { VMW(2); } else { VMW(0); }, NOP, LOADA(aX,1,0,0),
           if (more) STAGE_HT(B,0,1,T2), MFMAS(aY,1));
        // ph5: MFMA O/ks0/mf0-3 (aX); B<-O.B ks0; prefetch aY<-O.A mf4-7 ks0
        PH(NOP, LOADB(1,0), LOADA(aY,1,1,0), if (more) STAGE_HT(A,0,0,T2), MFMAS(aX,0));
        // ph6: MFMA O/ks0/mf4-7 (aY); prefetch aX<-O.A mf0-3 ks1
        PH(NOP, NOP, LOADA(aX,1,0,1), if (more) STAGE_HT(A,0,1,T2), MFMAS(aY,1));
        // ph7: MFMA O/ks1/mf0-3 (aX); B<-O.B ks1; prefetch aY<-O.A mf4-7 ks1
        PH(NOP, LOADB(1,1), LOADA(aY,1,1,1), if (more) STAGE_HT(B,1,0,T3), MFMAS(aX,0));
        // ph8: vm-gate next E-tile; MFMA O/ks1/mf4-7 (aY); prefetch aX<-E'.A mf0-3 ks0 (buf0)
        PH(if (more) { VMW(2); }, NOP, LOADA(aX,0,0,0),
           if (more) STAGE_HT(B,1,1,T3), MFMAS(aY,1));
    }

    // ---------------- epilogue ----------------
    const int colbase = n0 + wc * 64;
    if (G1) {
        unsigned short* c1 = (unsigned short*)Cout;
        #pragma unroll
        for (int nf = 0; nf < 4; ++nf) {
            const int col = colbase + nf * 16 + fr;
            const float bb = bias[(col >> 1) | ((col & 1) << 10)];  // invperm
            #pragma unroll
            for (int mf = 0; mf < 8; ++mf)
                #pragma unroll
                for (int r = 0; r < 4; ++r)
                    acc[mf][nf][r] += bb;
        }
        // fused stats: cos=r/|z|, sin=i/|z|; pair via lane^1
        float lc[4] = {0, 0, 0, 0}, ls[4] = {0, 0, 0, 0};
        #pragma unroll
        for (int nf = 0; nf < 4; ++nf)
            #pragma unroll
            for (int mf = 0; mf < 8; ++mf)
                #pragma unroll
                for (int r = 0; r < 4; ++r) {
                    const float v = acc[mf][nf][r];
                    const float oth = __shfl_xor(v, 1);
                    const float re = (fr & 1) ? oth : v;
                    const float im = (fr & 1) ? v : oth;
                    const float rq = rsqrtf(fmaxf(re * re + im * im, 1e-30f));
                    lc[nf] += re * rq;
                    ls[nf] += im * rq;
                }
        #pragma unroll
        for (int nf = 0; nf < 4; ++nf) {
            lc[nf] += __shfl_xor(lc[nf], 16); lc[nf] += __shfl_xor(lc[nf], 32);
            ls[nf] += __shfl_xor(ls[nf], 16); ls[nf] += __shfl_xor(ls[nf], 32);
        }
        if (lane < 16 && !(lane & 1)) {
            const int b = m0 >> 12;
            #pragma unroll
            for (int nf = 0; nf < 4; ++nf) {
                const int hh = (colbase + nf * 16 + fr) >> 1;
                atomicAdd(&sums[(b * 2 + 0) * H + hh], lc[nf]);
                atomicAdd(&sums[(b * 2 + 1) * H + hh], ls[nf]);
            }
        }
        // C store via LDS restage (As dead): stride 68 shorts, 16B stores
        unsigned short* cst = &As[0][0] + wid * 2048;
        const int row16 = lane >> 2;
        #pragma unroll
        for (int mf = 0; mf < 8; ++mf) {
            #pragma unroll
            for (int nf = 0; nf < 4; ++nf)
                #pragma unroll
                for (int r = 0; r < 4; ++r)
                    cst[(lg * 4 + r) * 68 + nf * 16 + fr] = f2bf(acc[mf][nf][r]);
            const size_t grow = (size_t)(m0 + wr * 128 + mf * 16 + row16);
            #pragma unroll
            for (int c = 0; c < 2; ++c) {
                const int chunk = (lane & 3) + c * 4;
                uint4 v = *(const uint4*)&cst[row16 * 68 + chunk * 8];
                *(uint4*)&c1[grow * N1 + colbase + chunk * 8] = v;
            }
        }
    } else {
        float* o = (float*)Cout;
        #pragma unroll
        for (int nf = 0; nf < 4; ++nf) {
            const int col = colbase + nf * 16 + fr;
            const float bb = bias[col];
            #pragma unroll
            for (int mf = 0; mf < 8; ++mf) {
                #pragma unroll
                for (int r = 0; r < 4; ++r) {
                    const size_t row = (size_t)(m0 + wr * 128 + mf * 16 + lg * 4 + r);
                    o[row * H + col] = acc[mf][nf][r] + bb;
                }
            }
        }
    }
}

// ---------- fold phase_shifts + means into P,Q per (b,h) ----------
__global__ void finalize_pq(const float* __restrict__ sums, const float* __restrict__ ps,
                            float* __restrict__ P, float* __restrict__ Q)
{
    int i = blockIdx.x * 256 + threadIdx.x;   // 8192
    int b = i >> 10, h = i & (H - 1);
    float mc = sums[(b * 2 + 0) * H + h] * (1.0f / SEQ);
    float ms = sums[(b * 2 + 1) * H + h] * (1.0f / SEQ);
    float cp = cosf(ps[h]), sp = sinf(ps[h]);
    P[i] = mc * cp + ms * sp;
    Q[i] = ms * cp - mc * sp;
}

// ---------- phase mix, in place, interleaved pairs ----------
__global__ __launch_bounds__(256) void phase_mix(
    unsigned short* __restrict__ c1, const float* __restrict__ P,
    const float* __restrict__ Q)
{
    const size_t total = (size_t)M_TOT * N1 / 8;
    for (size_t q = (size_t)blockIdx.x * 256 + threadIdx.x; q < total;
         q += (size_t)gridDim.x * 256) {
        const size_t m = q >> 8;
        const int off = ((int)q & 255) * 8;
        const int b = (int)(m >> 12);
        const int h0 = off >> 1;
        uint4* cu = (uint4*)c1;
        const size_t idx = ((size_t)m * N1 + off) >> 3;
        uint4 v = cu[idx];
        float4 Pv = *(const float4*)&P[b * H + h0];
        float4 Qv = *(const float4*)&Q[b * H + h0];
        const uint_t w[4] = { v.x, v.y, v.z, v.w };
        const float Pk[4] = { Pv.x, Pv.y, Pv.z, Pv.w };
        const float Qk[4] = { Qv.x, Qv.y, Qv.z, Qv.w };
        uint_t o[4];
        #pragma unroll
        for (int e = 0; e < 4; ++e) {
            float r  = bf2f(w[e] & 0xffff);
            float im = bf2f(w[e] >> 16);
            float tt = r * r + im * im;
            float minv = rsqrtf(fmaxf(tt, 1e-30f));
            float d = MIX * (r * Pk[e] + im * Qk[e]) * minv;
            float d2 = d * d;
            float cd = 1.0f - d2 * (0.5f - d2 * (1.0f / 24.0f));
            float sd = d * (1.0f - d2 * ((1.0f / 6.0f) - d2 * (1.0f / 120.0f)));
            float sc = sqrtf(tt + EPS) * minv;
            o[e] = (uint_t)f2bf(sc * (r * cd - im * sd))
                 | ((uint_t)f2bf(sc * (im * cd + r * sd)) << 16);
        }
        v.x = o[0]; v.y = o[1]; v.z = o[2]; v.w = o[3];
        cu[idx] = v;
    }
}

extern "C" void kernel_launch(void* const* d_in, const int* in_sizes, int n_in,
                              void* d_out, int out_size, void* d_ws, size_t ws_size,
                              hipStream_t stream) {
    const float* x  = (const float*)d_in[0];
    const float* Wt = (const float*)d_in[1];
    const float* bt = (const float*)d_in[2];
    const float* Wf = (const float*)d_in[3];
    const float* bf = (const float*)d_in[4];
    const float* ps = (const float*)d_in[5];
    float* out = (float*)d_out;

    const size_t c1_bytes   = (size_t)M_TOT * N1 * 2;
    const size_t wft_bytes  = (size_t)H * N1 * 2;
    const size_t sums_bytes = (size_t)BATCH * 2 * H * 4;
    const size_t pq_bytes   = (size_t)BATCH * H * 4;
    if (ws_size < c1_bytes + wft_bytes + sums_bytes + 2 * pq_bytes) return;

    unsigned short* c1  = (unsigned short*)d_ws;
    unsigned short* WfT = (unsigned short*)((char*)d_ws + c1_bytes);
    float* sums = (float*)((char*)d_ws + c1_bytes + wft_bytes);
    float* Pb   = (float*)((char*)d_ws + c1_bytes + wft_bytes + sums_bytes);
    float* Qb   = (float*)((char*)d_ws + c1_bytes + wft_bytes + sums_bytes + pq_bytes);

    // d_out doubles as scratch until gemm2 overwrites it
    unsigned short* xb  = (unsigned short*)d_out;                      // 64 Mi
    unsigned short* WtT = (unsigned short*)d_out + (size_t)M_TOT * H;  // 4 Mi

    hipMemsetAsync(sums, 0, sums_bytes, stream);

    cvt_f32_bf16<<<dim3((unsigned)(((size_t)M_TOT * H / 8 + 255) / 256)), 256, 0, stream>>>(
        x, xb, (size_t)M_TOT * H);
    transpose_wt<<<dim3(N1 / 64, H / 64), 256, 0, stream>>>(Wt, WtT);
    transpose_wf<<<dim3(H / 64, N1 / 64), 256, 0, stream>>>(Wf, WfT);

    gemm8<H, true><<<dim3(1024), 512, 0, stream>>>(xb, WtT, bt, (void*)c1, sums);

    finalize_pq<<<dim3(BATCH * H / 256), 256, 0, stream>>>(sums, ps, Pb, Qb);
    phase_mix<<<dim3(4096), 256, 0, stream>>>(c1, Pb, Qb);

    gemm8<N1, false><<<dim3(512), 512, 0, stream>>>(c1, WfT, bf, (void*)out, nullptr);
}